// Round 1
// baseline (900.243 us; speedup 1.0000x reference)
//
#include <hip/hip_runtime.h>

typedef unsigned short ushort_t;
typedef __bf16 bf16_t;
typedef bf16_t bf16x8 __attribute__((ext_vector_type(8)));
typedef float floatx4 __attribute__((ext_vector_type(4)));
typedef ushort_t ushort4v __attribute__((ext_vector_type(4)));
typedef ushort_t ushort8v __attribute__((ext_vector_type(8)));

static constexpr int B = 2, S = 2048, D = 2048;
static constexpr int H = 16, KVH = 4, HD = 256;

#define DEVFN static __device__ __forceinline__

DEVFN ushort_t f2b(float f) {
  union { float f; unsigned u; } x; x.f = f;
  unsigned r = x.u + 0x7fffu + ((x.u >> 16) & 1u);
  return (ushort_t)(r >> 16);
}
DEVFN float b2f(ushort_t h) {
  union { unsigned u; float f; } x; x.u = ((unsigned)h) << 16;
  return x.f;
}
DEVFN void gll16(const void* g, void* l) {
  __builtin_amdgcn_global_load_lds(
      (const __attribute__((address_space(1))) void*)g,
      (__attribute__((address_space(3))) void*)l, 16, 0, 0);
}

// ---------------------------------------------------------------- conversions
__global__ void k_cvt_bf16(const float* __restrict__ in, ushort_t* __restrict__ out, int n) {
  int i = (blockIdx.x * 256 + threadIdx.x) * 4;
  if (i >= n) return;
  float4 v = *(const float4*)(in + i);
  ushort4v o;
  o[0] = f2b(v.x); o[1] = f2b(v.y); o[2] = f2b(v.z); o[3] = f2b(v.w);
  *(ushort4v*)(out + i) = o;
}

// in: R x C fp32 row-major; out: C x R bf16 row-major (out[c][r] = in[r][c])
__global__ void k_transpose_cvt(const float* __restrict__ in, ushort_t* __restrict__ out,
                                int R, int C) {
  __shared__ float tile[32][33];
  const int bx = blockIdx.x * 32, by = blockIdx.y * 32;
  const int tx = threadIdx.x, ty = threadIdx.y;
#pragma unroll
  for (int i = 0; i < 32; i += 8)
    tile[ty + i][tx] = in[(size_t)(by + ty + i) * C + bx + tx];
  __syncthreads();
#pragma unroll
  for (int i = 0; i < 32; i += 8)
    out[(size_t)(bx + ty + i) * R + by + tx] = f2b(tile[tx][ty + i]);
}

// cos/sin table: tab[(s*128+dd)*2] = cos, +1 = sin
__global__ void k_rope_table(const int* __restrict__ pos_ids, float* __restrict__ tab) {
  int idx = blockIdx.x * 256 + threadIdx.x;  // S*128 total
  int s = idx >> 7, dd = idx & 127;
  float ang = (float)pos_ids[s] * exp2f((float)dd * (-13.287712379549449f / 128.0f));
  tab[idx * 2] = cosf(ang);
  tab[idx * 2 + 1] = sinf(ang);
}

// ---------------------------------------------------------------- GEMM (A row-major MxK, Bt row-major NxK)
template <bool OUT_BF16>
__global__ __launch_bounds__(256, 2)
void k_gemm_bt(const ushort_t* __restrict__ A, const ushort_t* __restrict__ Bt,
               void* __restrict__ Cout, int M, int N, int K) {
  // LDS tiles stored in MFMA-fragment chunk order: chunk c (16 rows x 32 k) = 64 lanes x 16B
  __shared__ ushort_t As[128 * 32];
  __shared__ ushort_t Bs[128 * 32];
  const int lane = threadIdx.x & 63;
  const int wave = threadIdx.x >> 6;
  const int lr = lane & 15, lq = lane >> 4;
  const size_t m0 = (size_t)blockIdx.x * 128;
  const size_t n0 = (size_t)blockIdx.y * 128;
  const int wm = (wave & 1) * 4;   // m-tile base (x16 rows)
  const int wn = (wave >> 1) * 4;  // n-tile base

  floatx4 acc[4][4];
#pragma unroll
  for (int i = 0; i < 4; i++)
#pragma unroll
    for (int j = 0; j < 4; j++) acc[i][j] = {0.f, 0.f, 0.f, 0.f};

  for (int kt = 0; kt < K; kt += 32) {
    __syncthreads();
#pragma unroll
    for (int i = 0; i < 2; i++) {
      const int c = wave * 2 + i;
      gll16(A + (m0 + c * 16 + lr) * K + kt + lq * 8, &As[c * 512 + lane * 8]);
      gll16(Bt + (n0 + c * 16 + lr) * K + kt + lq * 8, &Bs[c * 512 + lane * 8]);
    }
    __syncthreads();
    bf16x8 af[4], bfv[4];
#pragma unroll
    for (int i = 0; i < 4; i++) af[i] = *(const bf16x8*)&As[(wm + i) * 512 + lane * 8];
#pragma unroll
    for (int j = 0; j < 4; j++) bfv[j] = *(const bf16x8*)&Bs[(wn + j) * 512 + lane * 8];
#pragma unroll
    for (int i = 0; i < 4; i++)
#pragma unroll
      for (int j = 0; j < 4; j++)
        acc[i][j] = __builtin_amdgcn_mfma_f32_16x16x32_bf16(af[i], bfv[j], acc[i][j], 0, 0, 0);
  }

#pragma unroll
  for (int i = 0; i < 4; i++)
#pragma unroll
    for (int j = 0; j < 4; j++)
#pragma unroll
      for (int r = 0; r < 4; r++) {
        size_t row = m0 + (size_t)(wm + i) * 16 + lq * 4 + r;
        size_t col = n0 + (size_t)(wn + j) * 16 + lr;
        float v = acc[i][j][r];
        if (OUT_BF16) ((ushort_t*)Cout)[row * N + col] = f2b(v);
        else          ((float*)Cout)[row * N + col] = v;
      }
}

// ---------------------------------------------------------------- RMSNorm + RoPE (one wave per 256-row)
__global__ void k_norm_rope(ushort_t* __restrict__ x, const float* __restrict__ w,
                            const float* __restrict__ tab, int heads, float scale) {
  const int lane = threadIdx.x & 63;
  const size_t row = (size_t)blockIdx.x * 4 + (threadIdx.x >> 6);
  const int s = (int)((row / heads) % S);
  ushort_t* p = x + row * HD + lane * 4;
  ushort4v raw = *(const ushort4v*)p;
  float v[4];
  float ss = 0.f;
#pragma unroll
  for (int i = 0; i < 4; i++) { v[i] = b2f(raw[i]); ss += v[i] * v[i]; }
#pragma unroll
  for (int m = 1; m < 64; m <<= 1) ss += __shfl_xor(ss, m, 64);
  const float inv = rsqrtf(ss * (1.0f / HD) + 1e-6f);
  float4 wv = *(const float4*)(w + lane * 4);
  float y[4];
  y[0] = v[0] * inv * (1.0f + wv.x);
  y[1] = v[1] * inv * (1.0f + wv.y);
  y[2] = v[2] * inv * (1.0f + wv.z);
  y[3] = v[3] * inv * (1.0f + wv.w);
  float py[4];
#pragma unroll
  for (int i = 0; i < 4; i++) py[i] = __shfl_xor(y[i], 32, 64);
  const bool lo = (lane < 32);
  ushort4v ov;
#pragma unroll
  for (int i = 0; i < 4; i++) {
    int d = lane * 4 + i;
    int dd = d & 127;
    float2 cs = *(const float2*)(tab + ((size_t)s * 128 + dd) * 2);
    float rot = lo ? -py[i] : py[i];
    ov[i] = f2b((y[i] * cs.x + rot * cs.y) * scale);
  }
  *(ushort4v*)p = ov;
}

// ---------------------------------------------------------------- flash attention
// grid (S/64, H, B); block 256 = 4 waves x 16 q-rows; kv-tile 32
__global__ __launch_bounds__(256, 2)
void k_attn(const ushort_t* __restrict__ Q, const ushort_t* __restrict__ Kg,
            const ushort_t* __restrict__ Vg, ushort_t* __restrict__ O) {
  __shared__ ushort_t Ks[16 * 512];    // 16 chunks (nt 0..1, ks 0..7), fragment order
  __shared__ ushort_t Vrow[32 * 256];  // V tile, row-major
  __shared__ ushort_t Vs[16 * 512];    // V tile, B-fragment order (n = hd, k = kv)
  __shared__ ushort_t Ps[4][16 * 48];  // per-wave P, rows padded to 48 ushorts
  const int lane = threadIdx.x & 63, wave = threadIdx.x >> 6;
  const int lr = lane & 15, lq = lane >> 4;
  const int tid = threadIdx.x;
  const int qt = blockIdx.x, h = blockIdx.y, b = blockIdx.z;
  const int kvh = h >> 2;
  const int q0 = qt * 64 + wave * 16;

  bf16x8 qf[8];
  {
    const ushort_t* qp = Q + ((size_t)(b * S + q0 + lr) * H + h) * HD + lq * 8;
#pragma unroll
    for (int ks = 0; ks < 8; ks++) qf[ks] = *(const bf16x8*)(qp + ks * 32);
  }
  floatx4 o[16];
#pragma unroll
  for (int f = 0; f < 16; f++) o[f] = {0.f, 0.f, 0.f, 0.f};
  float m_i[4] = {-1e30f, -1e30f, -1e30f, -1e30f};
  float l_i[4] = {0.f, 0.f, 0.f, 0.f};

  const int ntiles = 2 * qt + 2;
  for (int kt = 0; kt < ntiles; kt++) {
    const int kbase = kt * 32;
    __syncthreads();  // prior compute/transpose reads finished
    // K chunks: c = nt*8+ks; wave stages 4
#pragma unroll
    for (int i = 0; i < 4; i++) {
      const int c = wave * 4 + i, nt = c >> 3, ks = c & 7;
      gll16(Kg + ((size_t)(b * S + kbase + nt * 16 + lr) * KVH + kvh) * HD + ks * 32 + lq * 8,
            &Ks[c * 512 + lane * 8]);
    }
    // V rows (row-major): each instr stages 2 rows
#pragma unroll
    for (int i = 0; i < 4; i++) {
      const int rb = (wave * 4 + i) * 2 + (lane >> 5);
      gll16(Vg + ((size_t)(b * S + kbase + rb) * KVH + kvh) * HD + (lane & 31) * 8,
            &Vrow[(wave * 4 + i) * 512 + lane * 8]);
    }
    __syncthreads();  // gll drained
    // transpose Vrow -> Vs (B-fragment order): thread t owns hd col t
#pragma unroll
    for (int w2 = 0; w2 < 4; w2++) {
      ushort8v pk;
#pragma unroll
      for (int j = 0; j < 8; j++) pk[j] = Vrow[(w2 * 8 + j) * 256 + tid];
      *(ushort8v*)&Vs[(tid >> 4) * 512 + ((tid & 15) + w2 * 16) * 8] = pk;
    }
    __syncthreads();  // Vs ready

    if (kbase <= q0 + 15) {
      floatx4 sacc[2];
      sacc[0] = {0.f, 0.f, 0.f, 0.f};
      sacc[1] = {0.f, 0.f, 0.f, 0.f};
#pragma unroll
      for (int nt = 0; nt < 2; nt++)
#pragma unroll
        for (int ks = 0; ks < 8; ks++) {
          bf16x8 kf = *(const bf16x8*)&Ks[(nt * 8 + ks) * 512 + lane * 8];
          sacc[nt] = __builtin_amdgcn_mfma_f32_16x16x32_bf16(qf[ks], kf, sacc[nt], 0, 0, 0);
        }
      if (kbase + 31 > q0) {  // diagonal-ish: causal mask
#pragma unroll
        for (int nt = 0; nt < 2; nt++)
#pragma unroll
          for (int r = 0; r < 4; r++)
            if (kbase + nt * 16 + lr > q0 + lq * 4 + r) sacc[nt][r] = -1e30f;
      }
      float mt[4], alpha[4], rs[4];
#pragma unroll
      for (int r = 0; r < 4; r++) mt[r] = fmaxf(sacc[0][r], sacc[1][r]);
#pragma unroll
      for (int m = 1; m < 16; m <<= 1)
#pragma unroll
        for (int r = 0; r < 4; r++) mt[r] = fmaxf(mt[r], __shfl_xor(mt[r], m, 64));
#pragma unroll
      for (int r = 0; r < 4; r++) {
        float mn = fmaxf(m_i[r], mt[r]);
        alpha[r] = __expf(m_i[r] - mn);
        m_i[r] = mn;
      }
#pragma unroll
      for (int nt = 0; nt < 2; nt++)
#pragma unroll
        for (int r = 0; r < 4; r++) sacc[nt][r] = __expf(sacc[nt][r] - m_i[r]);
#pragma unroll
      for (int r = 0; r < 4; r++) rs[r] = sacc[0][r] + sacc[1][r];
#pragma unroll
      for (int m = 1; m < 16; m <<= 1)
#pragma unroll
        for (int r = 0; r < 4; r++) rs[r] += __shfl_xor(rs[r], m, 64);
#pragma unroll
      for (int r = 0; r < 4; r++) l_i[r] = l_i[r] * alpha[r] + rs[r];
#pragma unroll
      for (int f = 0; f < 16; f++) {
        o[f][0] *= alpha[0]; o[f][1] *= alpha[1];
        o[f][2] *= alpha[2]; o[f][3] *= alpha[3];
      }
      // P: C-layout -> LDS -> A-layout
#pragma unroll
      for (int nt = 0; nt < 2; nt++)
#pragma unroll
        for (int r = 0; r < 4; r++)
          Ps[wave][(lq * 4 + r) * 48 + nt * 16 + lr] = f2b(sacc[nt][r]);
      bf16x8 pf = *(const bf16x8*)&Ps[wave][lr * 48 + lq * 8];
#pragma unroll
      for (int f = 0; f < 16; f++) {
        bf16x8 vf = *(const bf16x8*)&Vs[f * 512 + lane * 8];
        o[f] = __builtin_amdgcn_mfma_f32_16x16x32_bf16(pf, vf, o[f], 0, 0, 0);
      }
    }
  }
  float invl[4];
#pragma unroll
  for (int r = 0; r < 4; r++) invl[r] = 1.0f / l_i[r];
#pragma unroll
  for (int f = 0; f < 16; f++)
#pragma unroll
    for (int r = 0; r < 4; r++)
      O[((size_t)(b * S + q0 + lq * 4 + r) * H + h) * HD + f * 16 + lr] =
          f2b(o[f][r] * invl[r]);
}

// ---------------------------------------------------------------- launch
extern "C" void kernel_launch(void* const* d_in, const int* in_sizes, int n_in,
                              void* d_out, int out_size, void* d_ws, size_t ws_size,
                              hipStream_t stream) {
  const float* hs = (const float*)d_in[0];
  const float* Wq = (const float*)d_in[1];
  const float* Wk = (const float*)d_in[2];
  const float* Wv = (const float*)d_in[3];
  const float* Wo = (const float*)d_in[4];
  const float* qw = (const float*)d_in[5];
  const float* kw = (const float*)d_in[6];
  const int* pos = (const int*)d_in[7];
  float* out = (float*)d_out;

  char* ws = (char*)d_ws;
  size_t off = 0;
  auto alloc = [&](size_t bytes) {
    void* p = ws + off;
    off += (bytes + 255) & ~(size_t)255;
    return p;
  };
  ushort_t* Xb  = (ushort_t*)alloc((size_t)B * S * D * 2);
  ushort_t* Wqt = (ushort_t*)alloc((size_t)(H * HD) * D * 2);
  ushort_t* Wkt = (ushort_t*)alloc((size_t)(KVH * HD) * D * 2);
  ushort_t* Wvt = (ushort_t*)alloc((size_t)(KVH * HD) * D * 2);
  ushort_t* Wot = (ushort_t*)alloc((size_t)D * (H * HD) * 2);
  ushort_t* Qb  = (ushort_t*)alloc((size_t)B * S * H * HD * 2);
  ushort_t* Kb  = (ushort_t*)alloc((size_t)B * S * KVH * HD * 2);
  ushort_t* Vb  = (ushort_t*)alloc((size_t)B * S * KVH * HD * 2);
  ushort_t* Ab  = (ushort_t*)alloc((size_t)B * S * H * HD * 2);
  float*    tab = (float*)alloc((size_t)S * 128 * 2 * sizeof(float));

  k_cvt_bf16<<<(B * S * D / 4 + 255) / 256, 256, 0, stream>>>(hs, Xb, B * S * D);
  k_transpose_cvt<<<dim3((H * HD) / 32, D / 32), dim3(32, 8), 0, stream>>>(Wq, Wqt, D, H * HD);
  k_transpose_cvt<<<dim3((KVH * HD) / 32, D / 32), dim3(32, 8), 0, stream>>>(Wk, Wkt, D, KVH * HD);
  k_transpose_cvt<<<dim3((KVH * HD) / 32, D / 32), dim3(32, 8), 0, stream>>>(Wv, Wvt, D, KVH * HD);
  k_transpose_cvt<<<dim3(D / 32, (H * HD) / 32), dim3(32, 8), 0, stream>>>(Wo, Wot, H * HD, D);
  k_rope_table<<<S * 128 / 256, 256, 0, stream>>>(pos, tab);

  k_gemm_bt<true><<<dim3(B * S / 128, (H * HD) / 128), 256, 0, stream>>>(Xb, Wqt, Qb, B * S, H * HD, D);
  k_gemm_bt<true><<<dim3(B * S / 128, (KVH * HD) / 128), 256, 0, stream>>>(Xb, Wkt, Kb, B * S, KVH * HD, D);
  k_gemm_bt<true><<<dim3(B * S / 128, (KVH * HD) / 128), 256, 0, stream>>>(Xb, Wvt, Vb, B * S, KVH * HD, D);

  k_norm_rope<<<B * S * H / 4, 256, 0, stream>>>(Qb, qw, tab, H, 0.0625f);   // fold 1/sqrt(HD)
  k_norm_rope<<<B * S * KVH / 4, 256, 0, stream>>>(Kb, kw, tab, KVH, 1.0f);

  k_attn<<<dim3(S / 64, H, B), 256, 0, stream>>>(Qb, Kb, Vb, Ab);

  k_gemm_bt<false><<<dim3(B * S / 128, D / 128), 256, 0, stream>>>(Ab, Wot, out, B * S, D, H * HD);
}